// Round 8
// baseline (286.002 us; speedup 1.0000x reference)
//
#include <hip/hip_runtime.h>

typedef unsigned short u16;
typedef __attribute__((ext_vector_type(8))) short bf16x8;
typedef __attribute__((ext_vector_type(4))) float f32x4;

#define MFMA(a, b, c) __builtin_amdgcn_mfma_f32_16x16x32_bf16(a, b, c, 0, 0, 0)

// 2^x. clang builtin lowers to v_exp_f32 with compiler-managed TRANS hazards.
#if defined(__has_builtin)
#if __has_builtin(__builtin_amdgcn_exp2f)
#define EXP2(x) __builtin_amdgcn_exp2f(x)
#endif
#endif
#ifndef EXP2
#define EXP2(x) exp2f(x)
#endif

// async global->LDS, 16B per lane; lds ptr must be wave-uniform base.
#define ASYNC16(g, l)                                                      \
  __builtin_amdgcn_global_load_lds(                                        \
      (const __attribute__((address_space(1))) void*)(g),                  \
      (__attribute__((address_space(3))) void*)(l), 16, 0, 0)

#define SEQ 2048
#define KQW 2048  // kqv row width: K [0,1024) + Q [1024,2048); V goes straight to vt

__device__ __forceinline__ u16 f2bf(float x) {
  union { float f; unsigned u; } v; v.f = x;
  unsigned r = (v.u + 0x7fffu + ((v.u >> 16) & 1u)) >> 16;
  return (u16)r;
}

// pack two f32 -> bf16x2 (round-half-up), plain VALU ops (hazard-visible)
__device__ __forceinline__ unsigned pack_bf2(float a, float b) {
  unsigned ua = __float_as_uint(a) + 0x8000u;
  unsigned ub = __float_as_uint(b) + 0x8000u;
  return __builtin_amdgcn_perm(ub, ua, 0x07060302u);
}

// exp2 + pack 8 scores (two f32x4) into one bf16x8 A-fragment, in registers.
__device__ __forceinline__ bf16x8 exp_pack8(const f32x4 a, const f32x4 b) {
  union { unsigned u[4]; bf16x8 v; } r;
  r.u[0] = pack_bf2(EXP2(a[0]), EXP2(a[1]));
  r.u[1] = pack_bf2(EXP2(a[2]), EXP2(a[3]));
  r.u[2] = pack_bf2(EXP2(b[0]), EXP2(b[1]));
  r.u[3] = pack_bf2(EXP2(b[2]), EXP2(b[3]));
  return r.v;
}

// ---------------- fused preprocessing: both W transposes + x convert --------
//   blocks [0,3072)      : w_in  1024x3072 -> wT_in  (transpose + bf16)
//   blocks [3072,4096)   : w_out 1024x1024 -> wT_out
//   blocks [4096,12288)  : x fp32 -> xb bf16 (vectorized)
__global__ __launch_bounds__(256) void prep_fused(const float* __restrict__ w_in,
                                                  u16* __restrict__ wT_in,
                                                  const float* __restrict__ w_out,
                                                  u16* __restrict__ wT_out,
                                                  const float4* __restrict__ x,
                                                  uint2* __restrict__ xb) {
  int bid = blockIdx.x;
  int tid = threadIdx.x;
  if (bid >= 4096) {
    int idx = (bid - 4096) * 256 + tid;
    float4 v = x[idx];
    xb[idx] = make_uint2(pack_bf2(v.x, v.y), pack_bf2(v.z, v.w));
    return;
  }
  const float* in;
  u16* out;
  int R = 1024, C, bx, by;
  if (bid < 3072) {
    in = w_in; out = wT_in; C = 3072; bx = bid % 96; by = bid / 96;
  } else {
    int b2 = bid - 3072;
    in = w_out; out = wT_out; C = 1024; bx = b2 & 31; by = b2 >> 5;
  }
  __shared__ float tile[32][33];
  int tx = tid & 31, ty = tid >> 5;  // 32 x 8
  int c0 = bx * 32, r0 = by * 32;
#pragma unroll
  for (int i = 0; i < 32; i += 8)
    tile[ty + i][tx] = in[(size_t)(r0 + ty + i) * C + c0 + tx];
  __syncthreads();
#pragma unroll
  for (int i = 0; i < 32; i += 8)
    out[(size_t)(c0 + ty + i) * R + r0 + tx] = f2bf(tile[tx][ty + i]);
}

// ---------------- GEMM (m97 structure, 128^2): C = A * Bt^T + bias ----------
// 1D grid + bijective XCD swizzle (T1). Requires gridDim.x % 8 == 0.
// MODE 1: f32 out (GEMM2).
// MODE 2: GEMM1 fused output split -- bn<2048 writes bf16 kqv (ldc=2048);
//         bn>=2048 (V columns) writes vt[bh][d][s-perm] DIRECTLY via an LDS
//         transpose using v_transpose's verified kappa map. Saves the whole
//         v_transpose kernel (32 MB traffic + launch). LDS 65.5 KB -> still
//         2 blocks/CU. kappa offsets are compile-time (folded into ds_read
//         immediates).
#define BM 128
#define BN 128
#define BK 64

template <int MODE, int NBX>
__global__ __launch_bounds__(256, 2) void gemm_bt(const u16* __restrict__ A,
                                                  const u16* __restrict__ Bt,
                                                  const float* __restrict__ bias,
                                                  void* __restrict__ Cout,
                                                  u16* __restrict__ vtout,
                                                  int M, int N, int K, int ldc,
                                                  int sc_lo, int sc_hi, float qs) {
  __shared__ __align__(16) u16 As[BM * BK];
  __shared__ __align__(16) u16 Bs[BN * BK];
  int id = blockIdx.x;
  int cpx = gridDim.x >> 3;
  int swz = (id & 7) * cpx + (id >> 3);
  int bn = (swz % NBX) * BN, bm = (swz / NBX) * BM;
  int tid = threadIdx.x;
  int wave = tid >> 6, lane = tid & 63;
  int quad = lane >> 4, l16 = lane & 15;
  int wm = (wave >> 1) * 64, wn = (wave & 1) * 64;

  f32x4 acc[4][4] = {};

  int lrow = lane >> 3, lcol = (lane & 7) * 8;
  const u16* gA = A + (size_t)(bm + wave * 8 + lrow) * K + lcol;
  const u16* gB = Bt + (size_t)(bn + wave * 8 + lrow) * K + lcol;
  u16* lA = &As[wave * 8 * BK];
  u16* lB = &Bs[wave * 8 * BK];

  for (int k0 = 0; k0 < K; k0 += BK) {
#pragma unroll
    for (int p = 0; p < 4; ++p) {
      ASYNC16(gA + (size_t)p * 32 * K, lA + p * 32 * BK);
      ASYNC16(gB + (size_t)p * 32 * K, lB + p * 32 * BK);
    }
    gA += BK;
    gB += BK;
    __syncthreads();
#pragma unroll
    for (int kk = 0; kk < BK; kk += 32) {
      bf16x8 af[4], bfr[4];
#pragma unroll
      for (int i = 0; i < 4; ++i)
        af[i] = *(const bf16x8*)&As[(wm + 16 * i + l16) * BK + kk + quad * 8];
#pragma unroll
      for (int j = 0; j < 4; ++j)
        bfr[j] = *(const bf16x8*)&Bs[(wn + 16 * j + l16) * BK + kk + quad * 8];
#pragma unroll
      for (int i = 0; i < 4; ++i)
#pragma unroll
        for (int j = 0; j < 4; ++j)
          acc[i][j] = MFMA(af[i], bfr[j], acc[i][j]);
    }
    __syncthreads();
  }

  if constexpr (MODE == 2) {
    if (bn >= 2048) {
      // ---- fused V path: C-tile -> LDS -> vt[bh][d][s-perm] ----
      __shared__ u16 vtile[128][132];  // [v-col within block][s within block]
      // phase 1: each thread deposits its 64 scalars (bias added, no qs: V cols)
#pragma unroll
      for (int j = 0; j < 4; ++j) {
        int vc = wn + 16 * j + l16;
        float bv = bias[bn + vc];
#pragma unroll
        for (int i = 0; i < 4; ++i)
#pragma unroll
          for (int r = 0; r < 4; ++r)
            vtile[vc][wm + 16 * i + quad * 4 + r] = f2bf(acc[i][j][r] + bv);
      }
      __syncthreads();
      // phase 2: permuted, coalesced 16B writes. thread -> (vc, 64-key tile tt)
      int vc = tid >> 1, tt = tid & 1;
      int d = vc & 63;
      int b = bm >> 11, s0 = bm & 2047;
      int bh = b * 16 + ((bn - 2048) >> 6) + (vc >> 6);
      u16* row = vtout + (size_t)bh * 64 * SEQ + (size_t)d * SEQ + s0 + tt * 64;
#pragma unroll
      for (int c8 = 0; c8 < 8; ++c8) {
        u16 tmp[8];
#pragma unroll
        for (int e = 0; e < 8; ++e) {
          int pos = c8 * 8 + e;  // compile-time
          int k = 16 * (2 * (pos >> 5) + ((pos >> 2) & 1)) + ((pos >> 3) & 3) * 4 +
                  (pos & 3);  // kappa — verbatim from verified v_transpose
          tmp[e] = vtile[vc][tt * 64 + k];
        }
        *(uint4*)&row[c8 * 8] = *(uint4*)tmp;
      }
      return;
    }
  }

#pragma unroll
  for (int i = 0; i < 4; ++i) {
#pragma unroll
    for (int j = 0; j < 4; ++j) {
      int gn = bn + wn + 16 * j + l16;
      float bv = bias[gn];
      float sc = (gn >= sc_lo && gn < sc_hi) ? qs : 1.0f;
#pragma unroll
      for (int r = 0; r < 4; ++r) {
        int gm = bm + wm + 16 * i + quad * 4 + r;
        float v = (acc[i][j][r] + bv) * sc;
        if (MODE == 1)
          ((float*)Cout)[(size_t)gm * ldc + gn] = v;
        else
          ((u16*)Cout)[(size_t)gm * ldc + gn] = f2bf(v);
      }
    }
  }
}

// ---------------- flash attention v10: cross-tile pipeline ----------------
// (measured best: 90.6-92.0 us, zero bank conflicts — R5)
// 256 thr = 4 waves x 32 q-rows. Swapped QK^T (mfma(K,Q)) -> P lane-local,
// in-register exp/pack into PV A-fragments (kappa baked into the fused GEMM1
// V-epilogue). 2-tile software pipeline; K dbuf, V tribuf; 40 KiB LDS.
// kqv is now K+Q only (row width KQW=2048).
__global__ __launch_bounds__(256, 4) void attn_kernel(const u16* __restrict__ kqv,
                                                      const u16* __restrict__ vt,
                                                      u16* __restrict__ out) {
  int g = blockIdx.x;
  int bh = g & 63, qtile = g >> 6;
  int b = bh >> 4, h = bh & 15;
  int tid = threadIdx.x, wave = tid >> 6, lane = tid & 63;
  int quad = lane >> 4, l16 = lane & 15;

  __shared__ __align__(16) u16 Ks[2][64 * 64];   // dbuf, interleaved 8-row blocks
  __shared__ __align__(16) u16 Vts[3][64 * 64];  // tribuf, interleaved

  const u16* base = kqv + (size_t)b * SEQ * KQW;
  int hcol = h * 64;
  const u16* vbase = vt + (size_t)bh * 64 * SEQ;

  // Q fragments: wave owns 32 q-rows = 2 MFMA row-tiles, resident
  bf16x8 qf[2][2];
#pragma unroll
  for (int t = 0; t < 2; ++t) {
    int s = qtile * 128 + wave * 32 + t * 16 + l16;
    const u16* qrow = base + (size_t)s * KQW + 1024 + hcol;  // Q_OFF=1024
    qf[t][0] = *(const bf16x8*)(qrow + quad * 8);
    qf[t][1] = *(const bf16x8*)(qrow + 32 + quad * 8);
  }

  bf16x8 ones;
#pragma unroll
  for (int i = 0; i < 8; ++i) ones[i] = (short)0x3F80;

  f32x4 o[2][4] = {};
  f32x4 ol[2] = {};
  const f32x4 zf = {};  // persistent zero C-operand

  // staging lane mapping: lane l -> row l&7, 16B-chunk l>>3 of an 8-row group
  int prow = lane & 7;
  int pchk = (lane >> 3) * 8;  // elems

  // fragment-read addressing into the interleaved layout
  int rb2 = (l16 >> 3) * 512;  // 8-row sub-block offset (elems)
  int r8 = (l16 & 7) * 8;      // row-within-block offset (elems)

  // staging pointers: advance monotonically, one step per staged tile
  const u16* kg = base + hcol + (size_t)(wave * 16 + prow) * KQW + pchk;  // K_OFF=0
  const u16* vg = vbase + (size_t)(wave * 16 + prow) * SEQ + pchk;

#define STAGE_K(bi)                                      \
  do {                                                   \
    ASYNC16(kg, &Ks[bi][wave * 16 * 64]);                \
    ASYNC16(kg + (size_t)8 * KQW, &Ks[bi][(wave * 16 + 8) * 64]); \
    kg += (size_t)64 * KQW;                              \
  } while (0)
#define STAGE_V(bi)                                      \
  do {                                                   \
    ASYNC16(vg, &Vts[bi][wave * 16 * 64]);               \
    ASYNC16(vg + (size_t)8 * SEQ, &Vts[bi][(wave * 16 + 8) * 64]); \
    vg += 64;                                            \
  } while (0)

  const int NT = SEQ / 64;  // 32

  // prologue: tile 0 staged+drained; tile 1 in flight; QK^T(0)+exp -> pa
  STAGE_K(0);
  STAGE_V(0);
  __syncthreads();
  STAGE_K(1);
  STAGE_V(1);

  bf16x8 pa00, pa01, pa10, pa11;
  {
    const u16* ks = &Ks[0][0];
    f32x4 s0[4], s1[4];
#pragma unroll
    for (int j = 0; j < 4; ++j) {
      bf16x8 k0 = *(const bf16x8*)&ks[j * 1024 + rb2 + quad * 64 + r8];
      bf16x8 k1 = *(const bf16x8*)&ks[j * 1024 + rb2 + 256 + quad * 64 + r8];
      s0[j] = MFMA(k0, qf[0][0], zf);
      s0[j] = MFMA(k1, qf[0][1], s0[j]);
      s1[j] = MFMA(k0, qf[1][0], zf);
      s1[j] = MFMA(k1, qf[1][1], s1[j]);
    }
    pa00 = exp_pack8(s0[0], s0[1]);
    pa01 = exp_pack8(s0[2], s0[3]);
    pa10 = exp_pack8(s1[0], s1[1]);
    pa11 = exp_pack8(s1[2], s1[3]);
  }

  int v_rd = 0;  // Vts index holding V[t]
  int v_st = 2;  // Vts index receiving V[t+2]

  for (int t = 0; t < NT - 1; ++t) {
    // drains stage(t+1); fences all waves' reads of K[t] and V[t-1]
    __syncthreads();

    if (t + 2 < NT) {
      STAGE_K(t & 1);
      STAGE_V(v_st);
    }

    const u16* ks = &Ks[(t + 1) & 1][0];
    const u16* vs = &Vts[v_rd][0];

    __builtin_amdgcn_s_setprio(1);

    // QK^T(t+1): s[j] = mfma(K_j, Q_t); lane reg r = P[key=16j+quad*4+r][q=l16]
    f32x4 s0[4], s1[4];
#pragma unroll
    for (int j = 0; j < 4; ++j) {
      bf16x8 k0 = *(const bf16x8*)&ks[j * 1024 + rb2 + quad * 64 + r8];
      bf16x8 k1 = *(const bf16x8*)&ks[j * 1024 + rb2 + 256 + quad * 64 + r8];
      s0[j] = MFMA(k0, qf[0][0], zf);
      s0[j] = MFMA(k1, qf[0][1], s0[j]);
      s1[j] = MFMA(k0, qf[1][0], zf);
      s1[j] = MFMA(k1, qf[1][1], s1[j]);
    }

    // exp(t+1) -> next P-fragments (independent of PV below)
    bf16x8 pn00 = exp_pack8(s0[0], s0[1]);
    bf16x8 pn01 = exp_pack8(s0[2], s0[3]);
    bf16x8 pn10 = exp_pack8(s1[0], s1[1]);
    bf16x8 pn11 = exp_pack8(s1[2], s1[3]);

    // PV(t) with the PREVIOUS tile's pa: each V fragment read once.
#pragma unroll
    for (int d = 0; d < 4; ++d) {
      bf16x8 v0 = *(const bf16x8*)&vs[d * 1024 + rb2 + quad * 64 + r8];
      bf16x8 v1 = *(const bf16x8*)&vs[d * 1024 + rb2 + 256 + quad * 64 + r8];
      o[0][d] = MFMA(pa00, v0, o[0][d]);
      o[0][d] = MFMA(pa01, v1, o[0][d]);
      o[1][d] = MFMA(pa10, v0, o[1][d]);
      o[1][d] = MFMA(pa11, v1, o[1][d]);
    }
    ol[0] = MFMA(pa00, ones, ol[0]);
    ol[0] = MFMA(pa01, ones, ol[0]);
    ol[1] = MFMA(pa10, ones, ol[1]);
    ol[1] = MFMA(pa11, ones, ol[1]);

    __builtin_amdgcn_s_setprio(0);

    pa00 = pn00; pa01 = pn01; pa10 = pn10; pa11 = pn11;
    v_rd = (v_rd == 2) ? 0 : v_rd + 1;
    v_st = (v_st == 2) ? 0 : v_st + 1;
  }

  // peeled final tile: PV(NT-1) only (no further QK^T / staging in flight)
  __syncthreads();
  {
    const u16* vs = &Vts[v_rd][0];
    __builtin_amdgcn_s_setprio(1);
#pragma unroll
    for (int d = 0; d < 4; ++d) {
      bf16x8 v0 = *(const bf16x8*)&vs[d * 1024 + rb2 + quad * 64 + r8];
      bf16x8 v1 = *(const bf16x8*)&vs[d * 1024 + rb2 + 256 + quad * 64 + r8];
      o[0][d] = MFMA(pa00, v0, o[0][d]);
      o[0][d] = MFMA(pa01, v1, o[0][d]);
      o[1][d] = MFMA(pa10, v0, o[1][d]);
      o[1][d] = MFMA(pa11, v1, o[1][d]);
    }
    ol[0] = MFMA(pa00, ones, ol[0]);
    ol[0] = MFMA(pa01, ones, ol[0]);
    ol[1] = MFMA(pa10, ones, ol[1]);
    ol[1] = MFMA(pa11, ones, ol[1]);
    __builtin_amdgcn_s_setprio(0);
  }

  // epilogue: O /= l, merge heads
#pragma unroll
  for (int t = 0; t < 2; ++t)
#pragma unroll
    for (int r = 0; r < 4; ++r) {
      float inv = 1.0f / ol[t][r];
      int s = qtile * 128 + wave * 32 + t * 16 + quad * 4 + r;
      u16* orow = out + (size_t)(b * SEQ + s) * 1024 + hcol;
#pragma unroll
      for (int d = 0; d < 4; ++d) orow[16 * d + l16] = f2bf(o[t][d][r] * inv);
    }
#undef STAGE_K
#undef STAGE_V
}

extern "C" void kernel_launch(void* const* d_in, const int* in_sizes, int n_in,
                              void* d_out, int out_size, void* d_ws, size_t ws_size,
                              hipStream_t stream) {
  const float* x     = (const float*)d_in[0];
  const float* w_in  = (const float*)d_in[1];
  const float* b_in  = (const float*)d_in[2];
  const float* w_out = (const float*)d_in[3];
  const float* b_out = (const float*)d_in[4];
  float* outp = (float*)d_out;

  char* p = (char*)d_ws;
  u16* wT_in  = (u16*)p; p += (size_t)3072 * 1024 * 2;   //  6 MB
  u16* wT_out = (u16*)p; p += (size_t)1024 * 1024 * 2;   //  2 MB
  u16* xb     = (u16*)p; p += (size_t)8192 * 1024 * 2;   // 16 MB (live through GEMM1)
  u16* kqv    = (u16*)p; p += (size_t)8192 * 2048 * 2;   // 32 MB (K+Q only)
  u16* vtbuf  = (u16*)p; p += (size_t)64 * 64 * 2048 * 2; // 16 MB (written by GEMM1)
  u16* attn   = (u16*)p;                                  // 16 MB    => 88 MB total

  prep_fused<<<dim3(12288), dim3(256), 0, stream>>>(
      w_in, wT_in, w_out, wT_out, (const float4*)x, (uint2*)xb);

  const float QSCALE = 0.125f * 1.44269504088896f;
  // GEMM1: MODE 2 — K/Q -> kqv (ldc=2048), V -> vt directly (fused permute)
  gemm_bt<2, 3072 / BN><<<dim3((3072 / BN) * (8192 / BM)), 256, 0, stream>>>(
      xb, wT_in, b_in, (void*)kqv, vtbuf, 8192, 3072, 1024, 2048, 1024, 2048, QSCALE);

  attn_kernel<<<dim3(1024), 256, 0, stream>>>(kqv, vtbuf, attn);

  // GEMM2: MODE 1 — f32 out
  gemm_bt<1, 1024 / BN><<<dim3((1024 / BN) * (8192 / BM)), 256, 0, stream>>>(
      attn, wT_out, b_out, (void*)outp, nullptr, 8192, 1024, 1024, 1024, 0, 0, 1.0f);
}

// Round 9
// 285.917 us; speedup vs baseline: 1.0003x; 1.0003x over previous
//
#include <hip/hip_runtime.h>

typedef unsigned short u16;
typedef __attribute__((ext_vector_type(8))) short bf16x8;
typedef __attribute__((ext_vector_type(4))) float f32x4;

#define MFMA(a, b, c) __builtin_amdgcn_mfma_f32_16x16x32_bf16(a, b, c, 0, 0, 0)

// 2^x. clang builtin lowers to v_exp_f32 with compiler-managed TRANS hazards.
#if defined(__has_builtin)
#if __has_builtin(__builtin_amdgcn_exp2f)
#define EXP2(x) __builtin_amdgcn_exp2f(x)
#endif
#endif
#ifndef EXP2
#define EXP2(x) exp2f(x)
#endif

// async global->LDS, 16B per lane; lds ptr must be wave-uniform base.
#define ASYNC16(g, l)                                                      \
  __builtin_amdgcn_global_load_lds(                                        \
      (const __attribute__((address_space(1))) void*)(g),                  \
      (__attribute__((address_space(3))) void*)(l), 16, 0, 0)

#define SEQ 2048
#define KQW 2048  // kqv row width: K [0,1024) + Q [1024,2048); V goes straight to vt

__device__ __forceinline__ u16 f2bf(float x) {
  union { float f; unsigned u; } v; v.f = x;
  unsigned r = (v.u + 0x7fffu + ((v.u >> 16) & 1u)) >> 16;
  return (u16)r;
}

// pack two f32 -> bf16x2 (round-half-up), plain VALU ops (hazard-visible)
__device__ __forceinline__ unsigned pack_bf2(float a, float b) {
  unsigned ua = __float_as_uint(a) + 0x8000u;
  unsigned ub = __float_as_uint(b) + 0x8000u;
  return __builtin_amdgcn_perm(ub, ua, 0x07060302u);
}

// exp2 + pack 8 scores (two f32x4) into one bf16x8 A-fragment, in registers.
__device__ __forceinline__ bf16x8 exp_pack8(const f32x4 a, const f32x4 b) {
  union { unsigned u[4]; bf16x8 v; } r;
  r.u[0] = pack_bf2(EXP2(a[0]), EXP2(a[1]));
  r.u[1] = pack_bf2(EXP2(a[2]), EXP2(a[3]));
  r.u[2] = pack_bf2(EXP2(b[0]), EXP2(b[1]));
  r.u[3] = pack_bf2(EXP2(b[2]), EXP2(b[3]));
  return r.v;
}

// ---------------- fused preprocessing: both W transposes + x convert --------
//   blocks [0,3072)      : w_in  1024x3072 -> wT_in  (transpose + bf16)
//   blocks [3072,4096)   : w_out 1024x1024 -> wT_out
//   blocks [4096,12288)  : x fp32 -> xb bf16 (vectorized)
__global__ __launch_bounds__(256) void prep_fused(const float* __restrict__ w_in,
                                                  u16* __restrict__ wT_in,
                                                  const float* __restrict__ w_out,
                                                  u16* __restrict__ wT_out,
                                                  const float4* __restrict__ x,
                                                  uint2* __restrict__ xb) {
  int bid = blockIdx.x;
  int tid = threadIdx.x;
  if (bid >= 4096) {
    int idx = (bid - 4096) * 256 + tid;
    float4 v = x[idx];
    xb[idx] = make_uint2(pack_bf2(v.x, v.y), pack_bf2(v.z, v.w));
    return;
  }
  const float* in;
  u16* out;
  int R = 1024, C, bx, by;
  if (bid < 3072) {
    in = w_in; out = wT_in; C = 3072; bx = bid % 96; by = bid / 96;
  } else {
    int b2 = bid - 3072;
    in = w_out; out = wT_out; C = 1024; bx = b2 & 31; by = b2 >> 5;
  }
  __shared__ float tile[32][33];
  int tx = tid & 31, ty = tid >> 5;  // 32 x 8
  int c0 = bx * 32, r0 = by * 32;
#pragma unroll
  for (int i = 0; i < 32; i += 8)
    tile[ty + i][tx] = in[(size_t)(r0 + ty + i) * C + c0 + tx];
  __syncthreads();
#pragma unroll
  for (int i = 0; i < 32; i += 8)
    out[(size_t)(c0 + ty + i) * R + r0 + tx] = f2bf(tile[tx][ty + i]);
}

// ---------------- GEMM (m97 structure, 128^2): C = A * Bt^T + bias ----------
// 1D grid + bijective XCD swizzle (T1). Requires gridDim.x % 8 == 0.
// MODE 1: f32 out (GEMM2).
// MODE 2: GEMM1 fused output split -- bn<2048 writes bf16 kqv (ldc=2048);
//         bn>=2048 (V columns) writes vt[bh][d][s-perm] DIRECTLY via an LDS
//         transpose (kappa map verified in R8). R9: epilogue VECTORIZED --
//         kappa's structure (k = B0 + e for e<4, B0+16+(e-4) for e>=4, with
//         B0 = 32*(c8>>2)+4*(c8&3)) means each 16B output chunk is two
//         contiguous 8B LDS runs: 16 ds_write_b64 + 16 ds_read_b64 per thread
//         instead of R8's 128 scalar u16 ops (1.9e7 bank-conflict cycles).
#define BM 128
#define BN 128
#define BK 64

template <int MODE, int NBX>
__global__ __launch_bounds__(256, 2) void gemm_bt(const u16* __restrict__ A,
                                                  const u16* __restrict__ Bt,
                                                  const float* __restrict__ bias,
                                                  void* __restrict__ Cout,
                                                  u16* __restrict__ vtout,
                                                  int M, int N, int K, int ldc,
                                                  int sc_lo, int sc_hi, float qs) {
  __shared__ __align__(16) u16 As[BM * BK];
  __shared__ __align__(16) u16 Bs[BN * BK];
  int id = blockIdx.x;
  int cpx = gridDim.x >> 3;
  int swz = (id & 7) * cpx + (id >> 3);
  int bn = (swz % NBX) * BN, bm = (swz / NBX) * BM;
  int tid = threadIdx.x;
  int wave = tid >> 6, lane = tid & 63;
  int quad = lane >> 4, l16 = lane & 15;
  int wm = (wave >> 1) * 64, wn = (wave & 1) * 64;

  f32x4 acc[4][4] = {};

  int lrow = lane >> 3, lcol = (lane & 7) * 8;
  const u16* gA = A + (size_t)(bm + wave * 8 + lrow) * K + lcol;
  const u16* gB = Bt + (size_t)(bn + wave * 8 + lrow) * K + lcol;
  u16* lA = &As[wave * 8 * BK];
  u16* lB = &Bs[wave * 8 * BK];

  for (int k0 = 0; k0 < K; k0 += BK) {
#pragma unroll
    for (int p = 0; p < 4; ++p) {
      ASYNC16(gA + (size_t)p * 32 * K, lA + p * 32 * BK);
      ASYNC16(gB + (size_t)p * 32 * K, lB + p * 32 * BK);
    }
    gA += BK;
    gB += BK;
    __syncthreads();
#pragma unroll
    for (int kk = 0; kk < BK; kk += 32) {
      bf16x8 af[4], bfr[4];
#pragma unroll
      for (int i = 0; i < 4; ++i)
        af[i] = *(const bf16x8*)&As[(wm + 16 * i + l16) * BK + kk + quad * 8];
#pragma unroll
      for (int j = 0; j < 4; ++j)
        bfr[j] = *(const bf16x8*)&Bs[(wn + 16 * j + l16) * BK + kk + quad * 8];
#pragma unroll
      for (int i = 0; i < 4; ++i)
#pragma unroll
        for (int j = 0; j < 4; ++j)
          acc[i][j] = MFMA(af[i], bfr[j], acc[i][j]);
    }
    __syncthreads();
  }

  if constexpr (MODE == 2) {
    if (bn >= 2048) {
      // ---- fused V path: C-tile -> LDS -> vt[bh][d][s-perm], vectorized ----
      __shared__ u16 vtile[128][132];  // [v-col within block][s]; 264B rows, 8B-aligned
      // phase 1: 8B packed writes (4 consecutive s per acc[i][j])
#pragma unroll
      for (int j = 0; j < 4; ++j) {
        int vc = wn + 16 * j + l16;
        float bv = bias[bn + vc];
#pragma unroll
        for (int i = 0; i < 4; ++i) {
          u16 t4[4];
#pragma unroll
          for (int r = 0; r < 4; ++r) t4[r] = f2bf(acc[i][j][r] + bv);
          *(uint2*)&vtile[vc][wm + 16 * i + quad * 4] = *(uint2*)t4;
        }
      }
      __syncthreads();
      // phase 2: permuted 16B global writes; each = two contiguous 8B LDS reads
      int vc = tid >> 1, tt = tid & 1;
      int d = vc & 63;
      int b = bm >> 11, s0 = bm & 2047;
      int bh = b * 16 + ((bn - 2048) >> 6) + (vc >> 6);
      u16* row = vtout + (size_t)bh * 64 * SEQ + (size_t)d * SEQ + s0 + tt * 64;
      const u16* src = &vtile[vc][tt * 64];
#pragma unroll
      for (int c8 = 0; c8 < 8; ++c8) {
        int B0 = 32 * (c8 >> 2) + 4 * (c8 & 3);  // compile-time
        u16 tmp[8];
        *(uint2*)&tmp[0] = *(const uint2*)&src[B0];       // kappa run e=0..3
        *(uint2*)&tmp[4] = *(const uint2*)&src[B0 + 16];  // kappa run e=4..7
        *(uint4*)&row[c8 * 8] = *(uint4*)tmp;
      }
      return;
    }
  }

#pragma unroll
  for (int i = 0; i < 4; ++i) {
#pragma unroll
    for (int j = 0; j < 4; ++j) {
      int gn = bn + wn + 16 * j + l16;
      float bv = bias[gn];
      float sc = (gn >= sc_lo && gn < sc_hi) ? qs : 1.0f;
#pragma unroll
      for (int r = 0; r < 4; ++r) {
        int gm = bm + wm + 16 * i + quad * 4 + r;
        float v = (acc[i][j][r] + bv) * sc;
        if (MODE == 1)
          ((float*)Cout)[(size_t)gm * ldc + gn] = v;
        else
          ((u16*)Cout)[(size_t)gm * ldc + gn] = f2bf(v);
      }
    }
  }
}

// ---------------- flash attention v10: cross-tile pipeline ----------------
// (measured best: 90.6-92.0 us, zero bank conflicts)
// 256 thr = 4 waves x 32 q-rows. Swapped QK^T (mfma(K,Q)) -> P lane-local,
// in-register exp/pack into PV A-fragments (kappa baked into the fused GEMM1
// V-epilogue). 2-tile software pipeline; K dbuf, V tribuf; 40 KiB LDS.
// kqv is K+Q only (row width KQW=2048).
__global__ __launch_bounds__(256, 4) void attn_kernel(const u16* __restrict__ kqv,
                                                      const u16* __restrict__ vt,
                                                      u16* __restrict__ out) {
  int g = blockIdx.x;
  int bh = g & 63, qtile = g >> 6;
  int b = bh >> 4, h = bh & 15;
  int tid = threadIdx.x, wave = tid >> 6, lane = tid & 63;
  int quad = lane >> 4, l16 = lane & 15;

  __shared__ __align__(16) u16 Ks[2][64 * 64];   // dbuf, interleaved 8-row blocks
  __shared__ __align__(16) u16 Vts[3][64 * 64];  // tribuf, interleaved

  const u16* base = kqv + (size_t)b * SEQ * KQW;
  int hcol = h * 64;
  const u16* vbase = vt + (size_t)bh * 64 * SEQ;

  // Q fragments: wave owns 32 q-rows = 2 MFMA row-tiles, resident
  bf16x8 qf[2][2];
#pragma unroll
  for (int t = 0; t < 2; ++t) {
    int s = qtile * 128 + wave * 32 + t * 16 + l16;
    const u16* qrow = base + (size_t)s * KQW + 1024 + hcol;  // Q_OFF=1024
    qf[t][0] = *(const bf16x8*)(qrow + quad * 8);
    qf[t][1] = *(const bf16x8*)(qrow + 32 + quad * 8);
  }

  bf16x8 ones;
#pragma unroll
  for (int i = 0; i < 8; ++i) ones[i] = (short)0x3F80;

  f32x4 o[2][4] = {};
  f32x4 ol[2] = {};
  const f32x4 zf = {};  // persistent zero C-operand

  // staging lane mapping: lane l -> row l&7, 16B-chunk l>>3 of an 8-row group
  int prow = lane & 7;
  int pchk = (lane >> 3) * 8;  // elems

  // fragment-read addressing into the interleaved layout
  int rb2 = (l16 >> 3) * 512;  // 8-row sub-block offset (elems)
  int r8 = (l16 & 7) * 8;      // row-within-block offset (elems)

  // staging pointers: advance monotonically, one step per staged tile
  const u16* kg = base + hcol + (size_t)(wave * 16 + prow) * KQW + pchk;  // K_OFF=0
  const u16* vg = vbase + (size_t)(wave * 16 + prow) * SEQ + pchk;

#define STAGE_K(bi)                                      \
  do {                                                   \
    ASYNC16(kg, &Ks[bi][wave * 16 * 64]);                \
    ASYNC16(kg + (size_t)8 * KQW, &Ks[bi][(wave * 16 + 8) * 64]); \
    kg += (size_t)64 * KQW;                              \
  } while (0)
#define STAGE_V(bi)                                      \
  do {                                                   \
    ASYNC16(vg, &Vts[bi][wave * 16 * 64]);               \
    ASYNC16(vg + (size_t)8 * SEQ, &Vts[bi][(wave * 16 + 8) * 64]); \
    vg += 64;                                            \
  } while (0)

  const int NT = SEQ / 64;  // 32

  // prologue: tile 0 staged+drained; tile 1 in flight; QK^T(0)+exp -> pa
  STAGE_K(0);
  STAGE_V(0);
  __syncthreads();
  STAGE_K(1);
  STAGE_V(1);

  bf16x8 pa00, pa01, pa10, pa11;
  {
    const u16* ks = &Ks[0][0];
    f32x4 s0[4], s1[4];
#pragma unroll
    for (int j = 0; j < 4; ++j) {
      bf16x8 k0 = *(const bf16x8*)&ks[j * 1024 + rb2 + quad * 64 + r8];
      bf16x8 k1 = *(const bf16x8*)&ks[j * 1024 + rb2 + 256 + quad * 64 + r8];
      s0[j] = MFMA(k0, qf[0][0], zf);
      s0[j] = MFMA(k1, qf[0][1], s0[j]);
      s1[j] = MFMA(k0, qf[1][0], zf);
      s1[j] = MFMA(k1, qf[1][1], s1[j]);
    }
    pa00 = exp_pack8(s0[0], s0[1]);
    pa01 = exp_pack8(s0[2], s0[3]);
    pa10 = exp_pack8(s1[0], s1[1]);
    pa11 = exp_pack8(s1[2], s1[3]);
  }

  int v_rd = 0;  // Vts index holding V[t]
  int v_st = 2;  // Vts index receiving V[t+2]

  for (int t = 0; t < NT - 1; ++t) {
    // drains stage(t+1); fences all waves' reads of K[t] and V[t-1]
    __syncthreads();

    if (t + 2 < NT) {
      STAGE_K(t & 1);
      STAGE_V(v_st);
    }

    const u16* ks = &Ks[(t + 1) & 1][0];
    const u16* vs = &Vts[v_rd][0];

    __builtin_amdgcn_s_setprio(1);

    // QK^T(t+1): s[j] = mfma(K_j, Q_t); lane reg r = P[key=16j+quad*4+r][q=l16]
    f32x4 s0[4], s1[4];
#pragma unroll
    for (int j = 0; j < 4; ++j) {
      bf16x8 k0 = *(const bf16x8*)&ks[j * 1024 + rb2 + quad * 64 + r8];
      bf16x8 k1 = *(const bf16x8*)&ks[j * 1024 + rb2 + 256 + quad * 64 + r8];
      s0[j] = MFMA(k0, qf[0][0], zf);
      s0[j] = MFMA(k1, qf[0][1], s0[j]);
      s1[j] = MFMA(k0, qf[1][0], zf);
      s1[j] = MFMA(k1, qf[1][1], s1[j]);
    }

    // exp(t+1) -> next P-fragments (independent of PV below)
    bf16x8 pn00 = exp_pack8(s0[0], s0[1]);
    bf16x8 pn01 = exp_pack8(s0[2], s0[3]);
    bf16x8 pn10 = exp_pack8(s1[0], s1[1]);
    bf16x8 pn11 = exp_pack8(s1[2], s1[3]);

    // PV(t) with the PREVIOUS tile's pa: each V fragment read once.
#pragma unroll
    for (int d = 0; d < 4; ++d) {
      bf16x8 v0 = *(const bf16x8*)&vs[d * 1024 + rb2 + quad * 64 + r8];
      bf16x8 v1 = *(const bf16x8*)&vs[d * 1024 + rb2 + 256 + quad * 64 + r8];
      o[0][d] = MFMA(pa00, v0, o[0][d]);
      o[0][d] = MFMA(pa01, v1, o[0][d]);
      o[1][d] = MFMA(pa10, v0, o[1][d]);
      o[1][d] = MFMA(pa11, v1, o[1][d]);
    }
    ol[0] = MFMA(pa00, ones, ol[0]);
    ol[0] = MFMA(pa01, ones, ol[0]);
    ol[1] = MFMA(pa10, ones, ol[1]);
    ol[1] = MFMA(pa11, ones, ol[1]);

    __builtin_amdgcn_s_setprio(0);

    pa00 = pn00; pa01 = pn01; pa10 = pn10; pa11 = pn11;
    v_rd = (v_rd == 2) ? 0 : v_rd + 1;
    v_st = (v_st == 2) ? 0 : v_st + 1;
  }

  // peeled final tile: PV(NT-1) only (no further QK^T / staging in flight)
  __syncthreads();
  {
    const u16* vs = &Vts[v_rd][0];
    __builtin_amdgcn_s_setprio(1);
#pragma unroll
    for (int d = 0; d < 4; ++d) {
      bf16x8 v0 = *(const bf16x8*)&vs[d * 1024 + rb2 + quad * 64 + r8];
      bf16x8 v1 = *(const bf16x8*)&vs[d * 1024 + rb2 + 256 + quad * 64 + r8];
      o[0][d] = MFMA(pa00, v0, o[0][d]);
      o[0][d] = MFMA(pa01, v1, o[0][d]);
      o[1][d] = MFMA(pa10, v0, o[1][d]);
      o[1][d] = MFMA(pa11, v1, o[1][d]);
    }
    ol[0] = MFMA(pa00, ones, ol[0]);
    ol[0] = MFMA(pa01, ones, ol[0]);
    ol[1] = MFMA(pa10, ones, ol[1]);
    ol[1] = MFMA(pa11, ones, ol[1]);
    __builtin_amdgcn_s_setprio(0);
  }

  // epilogue: O /= l, merge heads
#pragma unroll
  for (int t = 0; t < 2; ++t)
#pragma unroll
    for (int r = 0; r < 4; ++r) {
      float inv = 1.0f / ol[t][r];
      int s = qtile * 128 + wave * 32 + t * 16 + quad * 4 + r;
      u16* orow = out + (size_t)(b * SEQ + s) * 1024 + hcol;
#pragma unroll
      for (int d = 0; d < 4; ++d) orow[16 * d + l16] = f2bf(o[t][d][r] * inv);
    }
#undef STAGE_K
#undef STAGE_V
}

extern "C" void kernel_launch(void* const* d_in, const int* in_sizes, int n_in,
                              void* d_out, int out_size, void* d_ws, size_t ws_size,
                              hipStream_t stream) {
  const float* x     = (const float*)d_in[0];
  const float* w_in  = (const float*)d_in[1];
  const float* b_in  = (const float*)d_in[2];
  const float* w_out = (const float*)d_in[3];
  const float* b_out = (const float*)d_in[4];
  float* outp = (float*)d_out;

  char* p = (char*)d_ws;
  u16* wT_in  = (u16*)p; p += (size_t)3072 * 1024 * 2;   //  6 MB
  u16* wT_out = (u16*)p; p += (size_t)1024 * 1024 * 2;   //  2 MB
  u16* xb     = (u16*)p; p += (size_t)8192 * 1024 * 2;   // 16 MB (live through GEMM1)
  u16* kqv    = (u16*)p; p += (size_t)8192 * 2048 * 2;   // 32 MB (K+Q only)
  u16* vtbuf  = (u16*)p; p += (size_t)64 * 64 * 2048 * 2; // 16 MB (written by GEMM1)
  u16* attn   = (u16*)p;                                  // 16 MB    => 88 MB total

  prep_fused<<<dim3(12288), dim3(256), 0, stream>>>(
      w_in, wT_in, w_out, wT_out, (const float4*)x, (uint2*)xb);

  const float QSCALE = 0.125f * 1.44269504088896f;
  // GEMM1: MODE 2 — K/Q -> kqv (ldc=2048), V -> vt directly (fused permute)
  gemm_bt<2, 3072 / BN><<<dim3((3072 / BN) * (8192 / BM)), 256, 0, stream>>>(
      xb, wT_in, b_in, (void*)kqv, vtbuf, 8192, 3072, 1024, 2048, 1024, 2048, QSCALE);

  attn_kernel<<<dim3(1024), 256, 0, stream>>>(kqv, vtbuf, attn);

  // GEMM2: MODE 1 — f32 out
  gemm_bt<1, 1024 / BN><<<dim3((1024 / BN) * (8192 / BM)), 256, 0, stream>>>(
      attn, wT_out, b_out, (void*)outp, nullptr, 8192, 1024, 1024, 1024, 0, 0, 1.0f);
}

// Round 12
// 263.040 us; speedup vs baseline: 1.0873x; 1.0870x over previous
//
#include <hip/hip_runtime.h>

typedef unsigned short u16;
typedef __attribute__((ext_vector_type(8))) short bf16x8;
typedef __attribute__((ext_vector_type(4))) float f32x4;

#define MFMA(a, b, c) __builtin_amdgcn_mfma_f32_16x16x32_bf16(a, b, c, 0, 0, 0)

// 2^x. clang builtin lowers to v_exp_f32 with compiler-managed TRANS hazards.
#if defined(__has_builtin)
#if __has_builtin(__builtin_amdgcn_exp2f)
#define EXP2(x) __builtin_amdgcn_exp2f(x)
#endif
#endif
#ifndef EXP2
#define EXP2(x) exp2f(x)
#endif

// async global->LDS, 16B per lane; lds ptr must be wave-uniform base.
#define ASYNC16(g, l)                                                      \
  __builtin_amdgcn_global_load_lds(                                        \
      (const __attribute__((address_space(1))) void*)(g),                  \
      (__attribute__((address_space(3))) void*)(l), 16, 0, 0)

#define SEQ 2048
#define KQW 2048  // kqv row width: K [0,1024) + Q [1024,2048); V goes straight to vt

__device__ __forceinline__ u16 f2bf(float x) {
  union { float f; unsigned u; } v; v.f = x;
  unsigned r = (v.u + 0x7fffu + ((v.u >> 16) & 1u)) >> 16;
  return (u16)r;
}

// pack two f32 -> bf16x2 (round-half-up), plain VALU ops (hazard-visible)
__device__ __forceinline__ unsigned pack_bf2(float a, float b) {
  unsigned ua = __float_as_uint(a) + 0x8000u;
  unsigned ub = __float_as_uint(b) + 0x8000u;
  return __builtin_amdgcn_perm(ub, ua, 0x07060302u);
}

// exp2 + pack 8 scores (two f32x4) into one bf16x8 A-fragment, in registers.
__device__ __forceinline__ bf16x8 exp_pack8(const f32x4 a, const f32x4 b) {
  union { unsigned u[4]; bf16x8 v; } r;
  r.u[0] = pack_bf2(EXP2(a[0]), EXP2(a[1]));
  r.u[1] = pack_bf2(EXP2(a[2]), EXP2(a[3]));
  r.u[2] = pack_bf2(EXP2(b[0]), EXP2(b[1]));
  r.u[3] = pack_bf2(EXP2(b[2]), EXP2(b[3]));
  return r.v;
}

// ---------------- fused preprocessing: both W transposes + x convert --------
//   blocks [0,3072)      : w_in  1024x3072 -> wT_in  (transpose + bf16)
//   blocks [3072,4096)   : w_out 1024x1024 -> wT_out
//   blocks [4096,12288)  : x fp32 -> xb bf16 (vectorized)
__global__ __launch_bounds__(256) void prep_fused(const float* __restrict__ w_in,
                                                  u16* __restrict__ wT_in,
                                                  const float* __restrict__ w_out,
                                                  u16* __restrict__ wT_out,
                                                  const float4* __restrict__ x,
                                                  uint2* __restrict__ xb) {
  int bid = blockIdx.x;
  int tid = threadIdx.x;
  if (bid >= 4096) {
    int idx = (bid - 4096) * 256 + tid;
    float4 v = x[idx];
    xb[idx] = make_uint2(pack_bf2(v.x, v.y), pack_bf2(v.z, v.w));
    return;
  }
  const float* in;
  u16* out;
  int R = 1024, C, bx, by;
  if (bid < 3072) {
    in = w_in; out = wT_in; C = 3072; bx = bid % 96; by = bid / 96;
  } else {
    int b2 = bid - 3072;
    in = w_out; out = wT_out; C = 1024; bx = b2 & 31; by = b2 >> 5;
  }
  __shared__ float tile[32][33];
  int tx = tid & 31, ty = tid >> 5;  // 32 x 8
  int c0 = bx * 32, r0 = by * 32;
#pragma unroll
  for (int i = 0; i < 32; i += 8)
    tile[ty + i][tx] = in[(size_t)(r0 + ty + i) * C + c0 + tx];
  __syncthreads();
#pragma unroll
  for (int i = 0; i < 32; i += 8)
    out[(size_t)(c0 + ty + i) * R + r0 + tx] = f2bf(tile[tx][ty + i]);
}

// ---------------- GEMM (m97 structure, 128^2): C = A * Bt^T + bias ----------
// 1D grid + bijective XCD swizzle (T1). Requires gridDim.x % 8 == 0.
// MODE 1: f32 out (GEMM2). Dynamic LDS = 32768 B (As+Bs).
// MODE 2: GEMM1 fused output split -- bn<2048 writes bf16 kqv (ldc=2048);
//         bn>=2048 (V columns) writes vt[bh][d][s-perm] DIRECTLY via an LDS
//         transpose (kappa verified R8). Dynamic LDS = 33792 B: vtile
//         (128x132 u16) ALIASES the dead As/Bs after the K-loop's final
//         barrier. R9's separate vtile (66560 B total) halved occupancy for
//         ALL GEMM1 blocks -- that was the whole 19us regression.
//         Phase-2 remap: 16 consecutive lanes write 16 consecutive 16B
//         chunks of ONE d-row (256B contiguous) -> coalesced vt writes.
// (R12: aliasing via extern __shared__ dynamic LDS -- the template-ternary
//  static array of R10/R11 correlated with container failures.)
#define BM 128
#define BN 128
#define BK 64

template <int MODE, int NBX>
__global__ __launch_bounds__(256, 2) void gemm_bt(const u16* __restrict__ A,
                                                  const u16* __restrict__ Bt,
                                                  const float* __restrict__ bias,
                                                  void* __restrict__ Cout,
                                                  u16* __restrict__ vtout,
                                                  int M, int N, int K, int ldc,
                                                  int sc_lo, int sc_hi, float qs) {
  extern __shared__ __align__(16) u16 smem[];  // MODE2: 33792 B; else 32768 B
  u16* As = smem;
  u16* Bs = smem + BM * BK;
  int id = blockIdx.x;
  int cpx = gridDim.x >> 3;
  int swz = (id & 7) * cpx + (id >> 3);
  int bn = (swz % NBX) * BN, bm = (swz / NBX) * BM;
  int tid = threadIdx.x;
  int wave = tid >> 6, lane = tid & 63;
  int quad = lane >> 4, l16 = lane & 15;
  int wm = (wave >> 1) * 64, wn = (wave & 1) * 64;

  f32x4 acc[4][4] = {};

  int lrow = lane >> 3, lcol = (lane & 7) * 8;
  const u16* gA = A + (size_t)(bm + wave * 8 + lrow) * K + lcol;
  const u16* gB = Bt + (size_t)(bn + wave * 8 + lrow) * K + lcol;
  u16* lA = &As[wave * 8 * BK];
  u16* lB = &Bs[wave * 8 * BK];

  for (int k0 = 0; k0 < K; k0 += BK) {
#pragma unroll
    for (int p = 0; p < 4; ++p) {
      ASYNC16(gA + (size_t)p * 32 * K, lA + p * 32 * BK);
      ASYNC16(gB + (size_t)p * 32 * K, lB + p * 32 * BK);
    }
    gA += BK;
    gB += BK;
    __syncthreads();
#pragma unroll
    for (int kk = 0; kk < BK; kk += 32) {
      bf16x8 af[4], bfr[4];
#pragma unroll
      for (int i = 0; i < 4; ++i)
        af[i] = *(const bf16x8*)&As[(wm + 16 * i + l16) * BK + kk + quad * 8];
#pragma unroll
      for (int j = 0; j < 4; ++j)
        bfr[j] = *(const bf16x8*)&Bs[(wn + 16 * j + l16) * BK + kk + quad * 8];
#pragma unroll
      for (int i = 0; i < 4; ++i)
#pragma unroll
        for (int j = 0; j < 4; ++j)
          acc[i][j] = MFMA(af[i], bfr[j], acc[i][j]);
    }
    __syncthreads();  // final iteration: all As/Bs reads complete past here
  }

  if constexpr (MODE == 2) {
    if (bn >= 2048) {
      // ---- fused V path: C-tile -> LDS (aliasing As/Bs) -> vt, coalesced ----
      u16* vtile = smem;  // 128 rows x 132 u16 (264B rows, 8B-aligned)
      // phase 1: 8B packed writes (4 consecutive s per acc[i][j])
#pragma unroll
      for (int j = 0; j < 4; ++j) {
        int vc = wn + 16 * j + l16;
        float bv = bias[bn + vc];
#pragma unroll
        for (int i = 0; i < 4; ++i) {
          u16 t4[4];
#pragma unroll
          for (int r = 0; r < 4; ++r) t4[r] = f2bf(acc[i][j][r] + bv);
          *(uint2*)&vtile[vc * 132 + wm + 16 * i + quad * 4] = *(uint2*)t4;
        }
      }
      __syncthreads();
      // phase 2: coalesced permuted writes. thread -> fixed 16B chunk c of 8
      // d-rows; 16 consecutive lanes cover 256B contiguous of one row.
      int b = bm >> 11, s0 = bm & 2047;
      int c = tid & 15, tt = c >> 3, c8 = c & 7;
      int B0 = 32 * (c8 >> 2) + 4 * (c8 & 3);  // kappa run base (two 8B runs)
#pragma unroll
      for (int vgi = 0; vgi < 8; ++vgi) {
        int vc = vgi * 16 + (tid >> 4);
        int d = vc & 63;
        int bh = b * 16 + ((bn - 2048) >> 6) + (vc >> 6);
        const u16* src = &vtile[vc * 132 + tt * 64];
        u16 tmp[8];
        *(uint2*)&tmp[0] = *(const uint2*)&src[B0];       // kappa run e=0..3
        *(uint2*)&tmp[4] = *(const uint2*)&src[B0 + 16];  // kappa run e=4..7
        *(uint4*)&vtout[(size_t)bh * 64 * SEQ + (size_t)d * SEQ + s0 + c * 8] =
            *(uint4*)tmp;
      }
      return;
    }
  }

#pragma unroll
  for (int i = 0; i < 4; ++i) {
#pragma unroll
    for (int j = 0; j < 4; ++j) {
      int gn = bn + wn + 16 * j + l16;
      float bv = bias[gn];
      float sc = (gn >= sc_lo && gn < sc_hi) ? qs : 1.0f;
#pragma unroll
      for (int r = 0; r < 4; ++r) {
        int gm = bm + wm + 16 * i + quad * 4 + r;
        float v = (acc[i][j][r] + bv) * sc;
        if (MODE == 1)
          ((float*)Cout)[(size_t)gm * ldc + gn] = v;
        else
          ((u16*)Cout)[(size_t)gm * ldc + gn] = f2bf(v);
      }
    }
  }
}

// ---------------- flash attention v10: cross-tile pipeline ----------------
// (measured best: 90.4-92.1 us, zero bank conflicts)
// 256 thr = 4 waves x 32 q-rows. Swapped QK^T (mfma(K,Q)) -> P lane-local,
// in-register exp/pack into PV A-fragments (kappa baked into the fused GEMM1
// V-epilogue). 2-tile software pipeline; K dbuf, V tribuf; 40 KiB LDS.
// kqv is K+Q only (row width KQW=2048).
__global__ __launch_bounds__(256, 4) void attn_kernel(const u16* __restrict__ kqv,
                                                      const u16* __restrict__ vt,
                                                      u16* __restrict__ out) {
  int g = blockIdx.x;
  int bh = g & 63, qtile = g >> 6;
  int b = bh >> 4, h = bh & 15;
  int tid = threadIdx.x, wave = tid >> 6, lane = tid & 63;
  int quad = lane >> 4, l16 = lane & 15;

  __shared__ __align__(16) u16 Ks[2][64 * 64];   // dbuf, interleaved 8-row blocks
  __shared__ __align__(16) u16 Vts[3][64 * 64];  // tribuf, interleaved

  const u16* base = kqv + (size_t)b * SEQ * KQW;
  int hcol = h * 64;
  const u16* vbase = vt + (size_t)bh * 64 * SEQ;

  // Q fragments: wave owns 32 q-rows = 2 MFMA row-tiles, resident
  bf16x8 qf[2][2];
#pragma unroll
  for (int t = 0; t < 2; ++t) {
    int s = qtile * 128 + wave * 32 + t * 16 + l16;
    const u16* qrow = base + (size_t)s * KQW + 1024 + hcol;  // Q_OFF=1024
    qf[t][0] = *(const bf16x8*)(qrow + quad * 8);
    qf[t][1] = *(const bf16x8*)(qrow + 32 + quad * 8);
  }

  bf16x8 ones;
#pragma unroll
  for (int i = 0; i < 8; ++i) ones[i] = (short)0x3F80;

  f32x4 o[2][4] = {};
  f32x4 ol[2] = {};
  const f32x4 zf = {};  // persistent zero C-operand

  // staging lane mapping: lane l -> row l&7, 16B-chunk l>>3 of an 8-row group
  int prow = lane & 7;
  int pchk = (lane >> 3) * 8;  // elems

  // fragment-read addressing into the interleaved layout
  int rb2 = (l16 >> 3) * 512;  // 8-row sub-block offset (elems)
  int r8 = (l16 & 7) * 8;      // row-within-block offset (elems)

  // staging pointers: advance monotonically, one step per staged tile
  const u16* kg = base + hcol + (size_t)(wave * 16 + prow) * KQW + pchk;  // K_OFF=0
  const u16* vg = vbase + (size_t)(wave * 16 + prow) * SEQ + pchk;

#define STAGE_K(bi)                                      \
  do {                                                   \
    ASYNC16(kg, &Ks[bi][wave * 16 * 64]);                \
    ASYNC16(kg + (size_t)8 * KQW, &Ks[bi][(wave * 16 + 8) * 64]); \
    kg += (size_t)64 * KQW;                              \
  } while (0)
#define STAGE_V(bi)                                      \
  do {                                                   \
    ASYNC16(vg, &Vts[bi][wave * 16 * 64]);               \
    ASYNC16(vg + (size_t)8 * SEQ, &Vts[bi][(wave * 16 + 8) * 64]); \
    vg += 64;                                            \
  } while (0)

  const int NT = SEQ / 64;  // 32

  // prologue: tile 0 staged+drained; tile 1 in flight; QK^T(0)+exp -> pa
  STAGE_K(0);
  STAGE_V(0);
  __syncthreads();
  STAGE_K(1);
  STAGE_V(1);

  bf16x8 pa00, pa01, pa10, pa11;
  {
    const u16* ks = &Ks[0][0];
    f32x4 s0[4], s1[4];
#pragma unroll
    for (int j = 0; j < 4; ++j) {
      bf16x8 k0 = *(const bf16x8*)&ks[j * 1024 + rb2 + quad * 64 + r8];
      bf16x8 k1 = *(const bf16x8*)&ks[j * 1024 + rb2 + 256 + quad * 64 + r8];
      s0[j] = MFMA(k0, qf[0][0], zf);
      s0[j] = MFMA(k1, qf[0][1], s0[j]);
      s1[j] = MFMA(k0, qf[1][0], zf);
      s1[j] = MFMA(k1, qf[1][1], s1[j]);
    }
    pa00 = exp_pack8(s0[0], s0[1]);
    pa01 = exp_pack8(s0[2], s0[3]);
    pa10 = exp_pack8(s1[0], s1[1]);
    pa11 = exp_pack8(s1[2], s1[3]);
  }

  int v_rd = 0;  // Vts index holding V[t]
  int v_st = 2;  // Vts index receiving V[t+2]

  for (int t = 0; t < NT - 1; ++t) {
    // drains stage(t+1); fences all waves' reads of K[t] and V[t-1]
    __syncthreads();

    if (t + 2 < NT) {
      STAGE_K(t & 1);
      STAGE_V(v_st);
    }

    const u16* ks = &Ks[(t + 1) & 1][0];
    const u16* vs = &Vts[v_rd][0];

    __builtin_amdgcn_s_setprio(1);

    // QK^T(t+1): s[j] = mfma(K_j, Q_t); lane reg r = P[key=16j+quad*4+r][q=l16]
    f32x4 s0[4], s1[4];
#pragma unroll
    for (int j = 0; j < 4; ++j) {
      bf16x8 k0 = *(const bf16x8*)&ks[j * 1024 + rb2 + quad * 64 + r8];
      bf16x8 k1 = *(const bf16x8*)&ks[j * 1024 + rb2 + 256 + quad * 64 + r8];
      s0[j] = MFMA(k0, qf[0][0], zf);
      s0[j] = MFMA(k1, qf[0][1], s0[j]);
      s1[j] = MFMA(k0, qf[1][0], zf);
      s1[j] = MFMA(k1, qf[1][1], s1[j]);
    }

    // exp(t+1) -> next P-fragments (independent of PV below)
    bf16x8 pn00 = exp_pack8(s0[0], s0[1]);
    bf16x8 pn01 = exp_pack8(s0[2], s0[3]);
    bf16x8 pn10 = exp_pack8(s1[0], s1[1]);
    bf16x8 pn11 = exp_pack8(s1[2], s1[3]);

    // PV(t) with the PREVIOUS tile's pa: each V fragment read once.
#pragma unroll
    for (int d = 0; d < 4; ++d) {
      bf16x8 v0 = *(const bf16x8*)&vs[d * 1024 + rb2 + quad * 64 + r8];
      bf16x8 v1 = *(const bf16x8*)&vs[d * 1024 + rb2 + 256 + quad * 64 + r8];
      o[0][d] = MFMA(pa00, v0, o[0][d]);
      o[0][d] = MFMA(pa01, v1, o[0][d]);
      o[1][d] = MFMA(pa10, v0, o[1][d]);
      o[1][d] = MFMA(pa11, v1, o[1][d]);
    }
    ol[0] = MFMA(pa00, ones, ol[0]);
    ol[0] = MFMA(pa01, ones, ol[0]);
    ol[1] = MFMA(pa10, ones, ol[1]);
    ol[1] = MFMA(pa11, ones, ol[1]);

    __builtin_amdgcn_s_setprio(0);

    pa00 = pn00; pa01 = pn01; pa10 = pn10; pa11 = pn11;
    v_rd = (v_rd == 2) ? 0 : v_rd + 1;
    v_st = (v_st == 2) ? 0 : v_st + 1;
  }

  // peeled final tile: PV(NT-1) only (no further QK^T / staging in flight)
  __syncthreads();
  {
    const u16* vs = &Vts[v_rd][0];
    __builtin_amdgcn_s_setprio(1);
#pragma unroll
    for (int d = 0; d < 4; ++d) {
      bf16x8 v0 = *(const bf16x8*)&vs[d * 1024 + rb2 + quad * 64 + r8];
      bf16x8 v1 = *(const bf16x8*)&vs[d * 1024 + rb2 + 256 + quad * 64 + r8];
      o[0][d] = MFMA(pa00, v0, o[0][d]);
      o[0][d] = MFMA(pa01, v1, o[0][d]);
      o[1][d] = MFMA(pa10, v0, o[1][d]);
      o[1][d] = MFMA(pa11, v1, o[1][d]);
    }
    ol[0] = MFMA(pa00, ones, ol[0]);
    ol[0] = MFMA(pa01, ones, ol[0]);
    ol[1] = MFMA(pa10, ones, ol[1]);
    ol[1] = MFMA(pa11, ones, ol[1]);
    __builtin_amdgcn_s_setprio(0);
  }

  // epilogue: O /= l, merge heads
#pragma unroll
  for (int t = 0; t < 2; ++t)
#pragma unroll
    for (int r = 0; r < 4; ++r) {
      float inv = 1.0f / ol[t][r];
      int s = qtile * 128 + wave * 32 + t * 16 + quad * 4 + r;
      u16* orow = out + (size_t)(b * SEQ + s) * 1024 + hcol;
#pragma unroll
      for (int d = 0; d < 4; ++d) orow[16 * d + l16] = f2bf(o[t][d][r] * inv);
    }
#undef STAGE_K
#undef STAGE_V
}

extern "C" void kernel_launch(void* const* d_in, const int* in_sizes, int n_in,
                              void* d_out, int out_size, void* d_ws, size_t ws_size,
                              hipStream_t stream) {
  const float* x     = (const float*)d_in[0];
  const float* w_in  = (const float*)d_in[1];
  const float* b_in  = (const float*)d_in[2];
  const float* w_out = (const float*)d_in[3];
  const float* b_out = (const float*)d_in[4];
  float* outp = (float*)d_out;

  char* p = (char*)d_ws;
  u16* wT_in  = (u16*)p; p += (size_t)3072 * 1024 * 2;   //  6 MB
  u16* wT_out = (u16*)p; p += (size_t)1024 * 1024 * 2;   //  2 MB
  u16* xb     = (u16*)p; p += (size_t)8192 * 1024 * 2;   // 16 MB (live through GEMM1)
  u16* kqv    = (u16*)p; p += (size_t)8192 * 2048 * 2;   // 32 MB (K+Q only)
  u16* vtbuf  = (u16*)p; p += (size_t)64 * 64 * 2048 * 2; // 16 MB (written by GEMM1)
  u16* attn   = (u16*)p;                                  // 16 MB    => 88 MB total

  prep_fused<<<dim3(12288), dim3(256), 0, stream>>>(
      w_in, wT_in, w_out, wT_out, (const float4*)x, (uint2*)xb);

  const float QSCALE = 0.125f * 1.44269504088896f;
  // GEMM1: MODE 2 — K/Q -> kqv (ldc=2048), V -> vt directly (fused permute).
  // Dynamic LDS 33792 B (vtile aliases As/Bs).
  gemm_bt<2, 3072 / BN><<<dim3((3072 / BN) * (8192 / BM)), 256, 33792, stream>>>(
      xb, wT_in, b_in, (void*)kqv, vtbuf, 8192, 3072, 1024, 2048, 1024, 2048, QSCALE);

  attn_kernel<<<dim3(1024), 256, 0, stream>>>(kqv, vtbuf, attn);

  // GEMM2: MODE 1 — f32 out. Dynamic LDS 32768 B.
  gemm_bt<1, 1024 / BN><<<dim3((1024 / BN) * (8192 / BM)), 256, 32768, stream>>>(
      attn, wT_out, b_out, (void*)outp, nullptr, 8192, 1024, 1024, 1024, 0, 0, 1.0f);
}